// Round 1
// baseline (2938.778 us; speedup 1.0000x reference)
//
#include <hip/hip_runtime.h>

#define BB 32
#define TT 16384
#define CC 16
#define GG 32

__device__ __forceinline__ float fast_sigmoid(float x) {
    float e = __expf(-x);                       // v_exp_f32 based
    return __builtin_amdgcn_rcpf(1.0f + e);     // v_rcp_f32
}

__device__ __forceinline__ float fast_tanh(float x) {
    float ax = fabsf(x);
    float e = __expf(2.0f * ax);                // inf for large ax -> handled
    float r = 1.0f - 2.0f * __builtin_amdgcn_rcpf(1.0f + e);
    return copysignf(r, x);
}

// Compute xr = relu(W1 * x[:, tt] + b1) at one time position.
// MODE==1: first layer, xin is (B,1,T) raw input (1 channel).
// else:    xin is (B,T,16) activation layout.
template <int MODE>
__device__ __forceinline__ void xr_at(const float* __restrict__ xin, int b, int tt,
                                      const float* __restrict__ w1,
                                      const float* __restrict__ b1,
                                      float* xr) {
    if (MODE == 1) {
        float v = xin[(size_t)b * TT + tt];
#pragma unroll
        for (int c = 0; c < CC; ++c) xr[c] = fmaxf(fmaf(w1[c], v, b1[c]), 0.0f);
    } else {
        const float4* p4 = (const float4*)(xin + ((size_t)(b * TT + tt)) * CC);
        float vin[CC];
#pragma unroll
        for (int j = 0; j < 4; ++j) {
            float4 v = p4[j];
            vin[j * 4 + 0] = v.x; vin[j * 4 + 1] = v.y;
            vin[j * 4 + 2] = v.z; vin[j * 4 + 3] = v.w;
        }
#pragma unroll
        for (int c = 0; c < CC; ++c) {
            float a = b1[c];
#pragma unroll
            for (int i = 0; i < CC; ++i) a = fmaf(w1[c * CC + i], vin[i], a);
            xr[c] = fmaxf(a, 0.0f);
        }
    }
}

// MODE: 0 = middle layer, 1 = first layer, 2 = last layer
template <int MODE>
__global__ __launch_bounds__(256) void wavenet_layer(
    const float* __restrict__ xin,   // (B,T,16) act, or (B,1,T) raw if MODE==1
    float* __restrict__ xout,        // (B,T,16) act (unused if MODE==2)
    float* __restrict__ skip,        // (B,16,T) accumulator == d_out
    const float* __restrict__ w1, const float* __restrict__ b1,
    const float* __restrict__ wf, const float* __restrict__ bf,
    const float* __restrict__ wg, const float* __restrict__ bg,
    const float* __restrict__ w2, const float* __restrict__ b2,
    int d) {
    int idx = blockIdx.x * 256 + threadIdx.x;
    int t = idx & (TT - 1);
    int b = idx >> 14;  // TT = 2^14
    int pl = d >> 1, pr = d - pl;
    int tL = t - pl, tR = t + pr;

    float xrL[CC], xrR[CC], xrC[CC];

    if (MODE != 2) xr_at<MODE>(xin, b, t, w1, b1, xrC);

    if (pl == 0) {
        // tap0 sits exactly on t (d==1 case): reuse / compute once
        if (MODE == 2) {
            xr_at<MODE>(xin, b, t, w1, b1, xrL);
        } else {
#pragma unroll
            for (int c = 0; c < CC; ++c) xrL[c] = xrC[c];
        }
    } else if (tL >= 0) {
        xr_at<MODE>(xin, b, tL, w1, b1, xrL);
    } else {
#pragma unroll
        for (int c = 0; c < CC; ++c) xrL[c] = 0.0f;
    }

    if (tR < TT) {
        xr_at<MODE>(xin, b, tR, w1, b1, xrR);
    } else {
#pragma unroll
        for (int c = 0; c < CC; ++c) xrR[c] = 0.0f;
    }

    // gated dilated conv: f/g = W{f,g}[o, i, k] over taps {tL, tR}
    float z[GG];
#pragma unroll
    for (int o = 0; o < GG; ++o) {
        float f = bf[o], g = bg[o];
#pragma unroll
        for (int i = 0; i < CC; ++i) {
            f = fmaf(wf[o * CC * 2 + i * 2 + 0], xrL[i], f);
            f = fmaf(wf[o * CC * 2 + i * 2 + 1], xrR[i], f);
            g = fmaf(wg[o * CC * 2 + i * 2 + 0], xrL[i], g);
            g = fmaf(wg[o * CC * 2 + i * 2 + 1], xrR[i], g);
        }
        z[o] = fast_tanh(f) * fast_sigmoid(g);
    }

    // output 1x1 conv (32->16) + relu, residual write, skip accumulate
    size_t xo_off = ((size_t)(b * TT + t)) * CC;
    size_t sk_base = (size_t)b * CC * TT + t;
#pragma unroll
    for (int c = 0; c < CC; ++c) {
        float a = b2[c];
#pragma unroll
        for (int o = 0; o < GG; ++o) a = fmaf(w2[c * GG + o], z[o], a);
        float z2 = fmaxf(a, 0.0f);
        if (MODE != 2) xout[xo_off + c] = xrC[c] + z2;
        size_t so = sk_base + (size_t)c * TT;
        if (MODE == 1)      skip[so] = z2;
        else if (MODE == 2) skip[so] = fmaxf(skip[so] + z2, 0.0f);
        else                skip[so] += z2;
    }
}

extern "C" void kernel_launch(void* const* d_in, const int* in_sizes, int n_in,
                              void* d_out, int out_size, void* d_ws, size_t ws_size,
                              hipStream_t stream) {
    const float* x        = (const float*)d_in[0];
    const float* w1_first = (const float*)d_in[1];
    const float* b1_first = (const float*)d_in[2];
    const float* w1_post  = (const float*)d_in[3];
    const float* b1_post  = (const float*)d_in[4];
    const float* wf       = (const float*)d_in[5];
    const float* bf       = (const float*)d_in[6];
    const float* wg       = (const float*)d_in[7];
    const float* bg       = (const float*)d_in[8];
    const float* w2       = (const float*)d_in[9];
    const float* b2       = (const float*)d_in[10];

    float* skip = (float*)d_out;
    float* X0 = (float*)d_ws;
    float* X1 = X0 + (size_t)BB * TT * CC;

    dim3 block(256);
    dim3 grid((BB * TT) / 256);

    for (int i = 0; i < 33; ++i) {
        int d = 1 << (i % 11);
        // layer i reads buffer (i+1)&1, writes buffer i&1 (layer 0 reads raw x)
        const float* xin = (i == 0) ? x : ((i & 1) ? X0 : X1);
        float* xout = (i & 1) ? X1 : X0;
        const float* w1  = (i == 0) ? w1_first : (w1_post + (size_t)(i - 1) * CC * CC);
        const float* b1p = (i == 0) ? b1_first : (b1_post + (size_t)(i - 1) * CC);
        const float* wfi = wf + (size_t)i * GG * CC * 2;
        const float* bfi = bf + (size_t)i * GG;
        const float* wgi = wg + (size_t)i * GG * CC * 2;
        const float* bgi = bg + (size_t)i * GG;
        const float* w2i = w2 + (size_t)i * CC * GG;
        const float* b2i = b2 + (size_t)i * CC;

        if (i == 0) {
            wavenet_layer<1><<<grid, block, 0, stream>>>(xin, xout, skip, w1, b1p,
                                                         wfi, bfi, wgi, bgi, w2i, b2i, d);
        } else if (i == 32) {
            wavenet_layer<2><<<grid, block, 0, stream>>>(xin, xout, skip, w1, b1p,
                                                         wfi, bfi, wgi, bgi, w2i, b2i, d);
        } else {
            wavenet_layer<0><<<grid, block, 0, stream>>>(xin, xout, skip, w1, b1p,
                                                         wfi, bfi, wgi, bgi, w2i, b2i, d);
        }
    }
}

// Round 5
// 1268.139 us; speedup vs baseline: 2.3174x; 2.3174x over previous
//
#include <hip/hip_runtime.h>

#define BB 32
#define TT 16384

typedef __attribute__((ext_vector_type(8))) short bf16x8;
typedef __attribute__((ext_vector_type(4))) short s16x4;
typedef __attribute__((ext_vector_type(4))) float f32x4;

#define MFMA(A, B, C) __builtin_amdgcn_mfma_f32_16x16x32_bf16((A), (B), (C), 0, 0, 0)

__device__ __forceinline__ unsigned short bf16_rne(float f) {
    unsigned int u = __float_as_uint(f);
    return (unsigned short)((u + 0x7FFF + ((u >> 16) & 1)) >> 16);
}
__device__ __forceinline__ unsigned short bf16_trunc(float f) {
    return (unsigned short)(__float_as_uint(f) >> 16);
}
__device__ __forceinline__ float bf16_to_f(unsigned short h) {
    return __uint_as_float(((unsigned int)h) << 16);
}

__device__ __forceinline__ float fast_sigmoid(float x) {
    float e = __expf(-x);
    return __builtin_amdgcn_rcpf(1.0f + e);
}
__device__ __forceinline__ float fast_tanh(float x) {
    float ax = fabsf(x);
    float e = __expf(2.0f * ax);
    float r = 1.0f - 2.0f * __builtin_amdgcn_rcpf(1.0f + e);
    return copysignf(r, x);
}

// LDS swizzle helpers: XOR full byte address within the per-wave region.
// xr pos-block = 64B, z pos-block = 128B; swz bits 4..6 keep 16B alignment.
__device__ __forceinline__ int swx(int p, int off) {
    return ((p << 6) + off) ^ ((p & 7) << 4);
}
__device__ __forceinline__ int swzz(int p, int off) {
    return ((p << 7) + off) ^ ((p & 7) << 4);
}

// ---------------------------------------------------------------------------
// Weight prep: pack A-fragments (bf16 hi/lo split) + per-lane bias vectors.
// Fragment convention (must match main kernel's B-frag convention):
//   lane l: row = l&15, group q = l>>4, elem j=0..7.
// conv1 (f0 hi / f1 lo):  src[j] = W1[o=row][ i = 8*(q&1)+j ]   (both K-halves)
// gate  (f2..f9):         src[j] = W{f,g}[16h+row][ 8*(q&1)+j ][ tap=q>>1 ]
// out   (f10 hi/f11 lo):  src[j] = W2[c=row][ o = 8q+j ]
// Bias sets: 0:b1  1:bf(o=4q+r) 2:bf(o=16+4q+r) 3:bg lo 4:bg hi 5:b2
// ---------------------------------------------------------------------------
__global__ void prep_kernel(const float* __restrict__ w1_first,
                            const float* __restrict__ b1_first,
                            const float* __restrict__ w1_post,
                            const float* __restrict__ b1_post,
                            const float* __restrict__ wf, const float* __restrict__ bfb,
                            const float* __restrict__ wg, const float* __restrict__ bgb,
                            const float* __restrict__ w2, const float* __restrict__ b2,
                            short* __restrict__ Wfrag, float* __restrict__ Bset) {
    int L = blockIdx.x;        // 0..32
    int l = threadIdx.x;       // 0..63
    int op = l & 15;
    int q = l >> 4;
    int i0 = (q & 1) << 3;
    int tap = q >> 1;

    float gbuf[6][8];
#pragma unroll
    for (int j = 0; j < 8; ++j) {
        gbuf[0][j] = (L == 0) ? 0.f
                   : w1_post[((size_t)(L - 1) * 16 + op) * 16 + i0 + j];
        gbuf[1][j] = wf[(((size_t)L * 32 + op) * 16 + i0 + j) * 2 + tap];
        gbuf[2][j] = wf[(((size_t)L * 32 + 16 + op) * 16 + i0 + j) * 2 + tap];
        gbuf[3][j] = wg[(((size_t)L * 32 + op) * 16 + i0 + j) * 2 + tap];
        gbuf[4][j] = wg[(((size_t)L * 32 + 16 + op) * 16 + i0 + j) * 2 + tap];
        gbuf[5][j] = w2[((size_t)L * 16 + op) * 32 + (q << 3) + j];
    }

    constexpr int gsel[12] = {0, 0, 1, 2, 1, 2, 3, 4, 3, 4, 5, 5};
    constexpr int hsel[12] = {1, 0, 1, 1, 0, 0, 1, 1, 0, 0, 1, 0};
#pragma unroll
    for (int f = 0; f < 12; ++f) {
        size_t base = (((size_t)L * 12 + f) * 64 + l) * 8;
#pragma unroll
        for (int j = 0; j < 8; ++j) {
            float v = gbuf[gsel[f]][j];
            unsigned short h = bf16_rne(v);
            Wfrag[base + j] = hsel[f] ? (short)h
                                      : (short)bf16_rne(v - bf16_to_f(h));
        }
    }

#pragma unroll
    for (int r = 0; r < 4; ++r) {
        int c = (q << 2) + r;
        float bv[6];
        bv[0] = (L == 0) ? b1_first[c] : b1_post[(size_t)(L - 1) * 16 + c];
        bv[1] = bfb[(size_t)L * 32 + c];
        bv[2] = bfb[(size_t)L * 32 + 16 + c];
        bv[3] = bgb[(size_t)L * 32 + c];
        bv[4] = bgb[(size_t)L * 32 + 16 + c];
        bv[5] = b2[(size_t)L * 16 + c];
#pragma unroll
        for (int s = 0; s < 6; ++s)
            Bset[(((size_t)L * 6 + s) * 64 + l) * 4 + r] = bv[s];
    }
}

// ---------------------------------------------------------------------------
// conv1 at one 16-pos segment -> relu'd xr in C/D layout (lane: pos=l&15,
// channels 4q..4q+3). OOB positions produce xr = 0 (matches zero padding of
// the dilated conv's input). Per-column validity is uniform across the 4
// lanes {p, p+16, p+32, p+48} that feed column p, so zero columns are exact.
// ---------------------------------------------------------------------------
template <int MODE>
__device__ __forceinline__ f32x4 conv1_eval(const float* __restrict__ xin,
                                            const float* __restrict__ w1f,
                                            int b, int tp, int q,
                                            f32x4 b1v, bf16x8 A1, bf16x8 A2) {
    const f32x4 zero = {0.f, 0.f, 0.f, 0.f};
    bool valid = ((unsigned)tp) < (unsigned)TT;
    f32x4 acc = valid ? b1v : zero;
    if (MODE == 1) {
        float xv = valid ? xin[(size_t)b * TT + tp] : 0.f;
        const float4* w4 = (const float4*)w1f;
        float4 w = w4[q];
        acc[0] = fmaf(w.x, xv, acc[0]);
        acc[1] = fmaf(w.y, xv, acc[1]);
        acc[2] = fmaf(w.z, xv, acc[2]);
        acc[3] = fmaf(w.w, xv, acc[3]);
    } else {
        int tpc = valid ? tp : 0;
        const f32x4* xp =
            (const f32x4*)(xin + (((size_t)b * TT + tpc) << 4) + ((q & 1) << 3));
        f32x4 v0 = xp[0], v1 = xp[1];
        if (!valid) { v0 = zero; v1 = zero; }
        bf16x8 bb;
#pragma unroll
        for (int j = 0; j < 8; ++j) {
            float fv = (j < 4) ? v0[j] : v1[j - 4];
            unsigned short h = bf16_trunc(fv);
            bb[j] = (q < 2) ? (short)h : (short)bf16_rne(fv - bf16_to_f(h));
        }
        acc = MFMA(A1, bb, acc);
        acc = MFMA(A2, bb, acc);
    }
#pragma unroll
    for (int r = 0; r < 4; ++r) acc[r] = fmaxf(acc[r], 0.f);
    return acc;
}

// MODE: 0 = middle, 1 = first (raw (B,1,T) input, conv1 via VALU), 2 = last
template <int MODE>
__global__ __launch_bounds__(256) void wn_layer(
    const float* __restrict__ xin, float* __restrict__ xout,
    float* __restrict__ skip, float* __restrict__ dout,
    const short* __restrict__ WfragL, const float* __restrict__ BsetL,
    const float* __restrict__ w1f, int d) {
    __shared__ short sm[8192];  // 16 KB: [0,8K) xr segs (2KB/wave), [8K,16K) z

    const int tid = threadIdx.x;
    const int wave = tid >> 6, lane = tid & 63;
    const int p = lane & 15, q = lane >> 4;

    // bijective XCD swizzle (8192 blocks % 8 == 0)
    const int blk = ((blockIdx.x & 7) << 10) + (blockIdx.x >> 3);
    const int b = blk >> 8;
    const int tbase = ((blk & 255) << 6) + (wave << 4);
    const int pl = d >> 1, pr = d - pl;

    char* xrb = (char*)sm + wave * 2048;
    char* zb = (char*)sm + 8192 + wave * 2048;

    const bf16x8* WF = (const bf16x8*)WfragL;
    const f32x4* BS = (const f32x4*)BsetL;

    const f32x4 b1v = BS[lane];
    bf16x8 A1 = {0, 0, 0, 0, 0, 0, 0, 0};
    bf16x8 A2 = {0, 0, 0, 0, 0, 0, 0, 0};
    if (MODE != 1) { A1 = WF[lane]; A2 = WF[64 + lane]; }

    // --- conv1 at the two tap segments -> LDS (hi at +0..31, lo at +32..63)
#pragma unroll
    for (int g = 0; g < 2; ++g) {
        int ts = tbase + (g ? pr : -pl);
        f32x4 xr = conv1_eval<MODE>(xin, w1f, b, ts + p, q, b1v, A1, A2);
        s16x4 sh, sl;
#pragma unroll
        for (int r = 0; r < 4; ++r) {
            unsigned short h = bf16_trunc(xr[r]);
            sh[r] = (short)h;
            sl[r] = (short)bf16_rne(xr[r] - bf16_to_f(h));
        }
        *(s16x4*)(xrb + (g << 10) + swx(p, (q << 3))) = sh;
        *(s16x4*)(xrb + (g << 10) + swx(p, 32 + (q << 3))) = sl;
    }

    f32x4 xrC = {0.f, 0.f, 0.f, 0.f};
    if (MODE != 2)
        xrC = conv1_eval<MODE>(xin, w1f, b, tbase + p, q, b1v, A1, A2);

    // --- gated dilated conv (f,g): 3 split-MFMAs per o-half each
    f32x4 f0 = BS[64 + lane], f1 = BS[128 + lane];
    f32x4 g0 = BS[192 + lane], g1 = BS[256 + lane];

    const char* ga = xrb + ((q >> 1) << 10);
    bf16x8 bHi = *(const bf16x8*)(ga + swx(p, (q & 1) << 4));
    bf16x8 bLo = *(const bf16x8*)(ga + swx(p, 32 + ((q & 1) << 4)));

    bf16x8 AfH0 = WF[2 * 64 + lane], AfH1 = WF[3 * 64 + lane];
    bf16x8 AfL0 = WF[4 * 64 + lane], AfL1 = WF[5 * 64 + lane];
    bf16x8 AgH0 = WF[6 * 64 + lane], AgH1 = WF[7 * 64 + lane];
    bf16x8 AgL0 = WF[8 * 64 + lane], AgL1 = WF[9 * 64 + lane];

    f0 = MFMA(AfH0, bHi, f0); f0 = MFMA(AfH0, bLo, f0); f0 = MFMA(AfL0, bHi, f0);
    f1 = MFMA(AfH1, bHi, f1); f1 = MFMA(AfH1, bLo, f1); f1 = MFMA(AfL1, bHi, f1);
    g0 = MFMA(AgH0, bHi, g0); g0 = MFMA(AgH0, bLo, g0); g0 = MFMA(AgL0, bHi, g0);
    g1 = MFMA(AgH1, bHi, g1); g1 = MFMA(AgH1, bLo, g1); g1 = MFMA(AgL1, bHi, g1);

    // --- z = tanh(f)*sigmoid(g); stage split-bf16 to LDS
#pragma unroll
    for (int h = 0; h < 2; ++h) {
        s16x4 zh, zl;
#pragma unroll
        for (int r = 0; r < 4; ++r) {
            float fv = h ? f1[r] : f0[r];
            float gv = h ? g1[r] : g0[r];
            float zv = fast_tanh(fv) * fast_sigmoid(gv);
            unsigned short hh = bf16_trunc(zv);
            zh[r] = (short)hh;
            zl[r] = (short)bf16_rne(zv - bf16_to_f(hh));
        }
        *(s16x4*)(zb + swzz(p, (h << 5) + (q << 3))) = zh;
        *(s16x4*)(zb + swzz(p, 64 + (h << 5) + (q << 3))) = zl;
    }

    // --- output 1x1 conv (32->16) + relu
    f32x4 z2 = BS[320 + lane];
    bf16x8 zHi = *(const bf16x8*)(zb + swzz(p, q << 4));
    bf16x8 zLo = *(const bf16x8*)(zb + swzz(p, 64 + (q << 4)));
    bf16x8 A2H = WF[10 * 64 + lane], A2L = WF[11 * 64 + lane];
    z2 = MFMA(A2H, zHi, z2);
    z2 = MFMA(A2H, zLo, z2);
    z2 = MFMA(A2L, zHi, z2);
#pragma unroll
    for (int r = 0; r < 4; ++r) z2[r] = fmaxf(z2[r], 0.f);

    // --- epilogue
    size_t xidx = (((size_t)b * TT + tbase + p) << 4) + (q << 2);
    if (MODE != 2) {
        f32x4 xo;
#pragma unroll
        for (int r = 0; r < 4; ++r) xo[r] = xrC[r] + z2[r];
        *(f32x4*)(xout + xidx) = xo;
        if (MODE == 1) {
            *(f32x4*)(skip + xidx) = z2;
        } else {
            f32x4 s = *(const f32x4*)(skip + xidx);
#pragma unroll
            for (int r = 0; r < 4; ++r) s[r] += z2[r];
            *(f32x4*)(skip + xidx) = s;
        }
    } else {
        f32x4 s = *(const f32x4*)(skip + xidx);
        size_t ob = (size_t)b * (16 * (size_t)TT) + (size_t)(q << 2) * TT + (tbase + p);
#pragma unroll
        for (int r = 0; r < 4; ++r)
            dout[ob + (size_t)r * TT] = fmaxf(s[r] + z2[r], 0.f);
    }
}

extern "C" void kernel_launch(void* const* d_in, const int* in_sizes, int n_in,
                              void* d_out, int out_size, void* d_ws, size_t ws_size,
                              hipStream_t stream) {
    const float* x        = (const float*)d_in[0];
    const float* w1_first = (const float*)d_in[1];
    const float* b1_first = (const float*)d_in[2];
    const float* w1_post  = (const float*)d_in[3];
    const float* b1_post  = (const float*)d_in[4];
    const float* wf       = (const float*)d_in[5];
    const float* bf       = (const float*)d_in[6];
    const float* wg       = (const float*)d_in[7];
    const float* bg       = (const float*)d_in[8];
    const float* w2       = (const float*)d_in[9];
    const float* b2       = (const float*)d_in[10];

    float* X0 = (float*)d_ws;                                   // 33.55 MB
    float* SK = (float*)((char*)d_ws + 33554432);               // 33.55 MB
    short* Wfrag = (short*)((char*)d_ws + 67108864);            // 405,504 B
    float* Bset = (float*)((char*)d_ws + 67514368);             // 202,752 B
    float* XD = (float*)d_out;  // ping-pong buffer; overwritten by final layer

    prep_kernel<<<33, 64, 0, stream>>>(w1_first, b1_first, w1_post, b1_post,
                                       wf, bf, wg, bg, w2, b2, Wfrag, Bset);

    dim3 block(256);
    dim3 grid(BB * TT / 64);  // 8192

    for (int i = 0; i < 33; ++i) {
        int d = 1 << (i % 11);
        const float* xin = (i == 0) ? x : ((i & 1) ? XD : X0);
        float* xout = (i & 1) ? X0 : XD;  // layer 0 writes XD
        const short* WfL = Wfrag + (size_t)i * 12 * 64 * 8;
        const float* BsL = Bset + (size_t)i * 6 * 64 * 4;

        if (i == 0) {
            wn_layer<1><<<grid, block, 0, stream>>>(xin, xout, SK, (float*)d_out,
                                                    WfL, BsL, w1_first, d);
        } else if (i == 32) {
            wn_layer<2><<<grid, block, 0, stream>>>(xin, nullptr, SK, (float*)d_out,
                                                    WfL, BsL, w1_first, d);
        } else {
            wn_layer<0><<<grid, block, 0, stream>>>(xin, xout, SK, (float*)d_out,
                                                    WfL, BsL, w1_first, d);
        }
    }
}

// Round 6
// 932.425 us; speedup vs baseline: 3.1518x; 1.3600x over previous
//
#include <hip/hip_runtime.h>

#define BB 32
#define TT 16384

typedef __attribute__((ext_vector_type(8))) short bf16x8;
typedef __attribute__((ext_vector_type(4))) short s16x4;
typedef __attribute__((ext_vector_type(4))) float f32x4;

#define MFMA(A, B, C) __builtin_amdgcn_mfma_f32_16x16x32_bf16((A), (B), (C), 0, 0, 0)

__device__ __forceinline__ unsigned short bf16_rne(float f) {
    unsigned int u = __float_as_uint(f);
    return (unsigned short)((u + 0x7FFF + ((u >> 16) & 1)) >> 16);
}
__device__ __forceinline__ float bf16_to_f(unsigned short h) {
    return __uint_as_float(((unsigned int)h) << 16);
}
__device__ __forceinline__ s16x4 pack4(f32x4 v) {
    s16x4 r;
#pragma unroll
    for (int i = 0; i < 4; ++i) r[i] = (short)bf16_rne(v[i]);
    return r;
}

__device__ __forceinline__ float fast_sigmoid(float x) {
    float e = __expf(-x);
    return __builtin_amdgcn_rcpf(1.0f + e);
}
__device__ __forceinline__ float fast_tanh(float x) {
    float ax = fabsf(x);
    float e = __expf(2.0f * ax);
    float r = 1.0f - 2.0f * __builtin_amdgcn_rcpf(1.0f + e);
    return copysignf(r, x);
}

// ---------------------------------------------------------------------------
// Weight prep: 7 fragments/layer + 6 bias sets/layer.
// Fragment convention (A and B share the same (q,j)->k mapping):
//   lane l: row = l&15 (out-ch), q = l>>4, elem j=0..7.
// f0/f1: conv1 W1 hi/lo:  src[j] = W1[row][8*(q&1)+j]  (replicated over q>>1)
// f2..f5: gate Wf h0, Wf h1, Wg h0, Wg h1 (single rne):
//         src[j] = W[16h+row][8*(q&1)+j][tap=q>>1]
// f6: out W2 (single rne): src[j] = W2[row][8q+j]
// Bias sets: 0:b1  1:bf h0  2:bf h1  3:bg h0  4:bg h1  5:b2  (c = 4q+r)
// ---------------------------------------------------------------------------
__global__ void prep_kernel(const float* __restrict__ w1_first,
                            const float* __restrict__ b1_first,
                            const float* __restrict__ w1_post,
                            const float* __restrict__ b1_post,
                            const float* __restrict__ wf, const float* __restrict__ bfb,
                            const float* __restrict__ wg, const float* __restrict__ bgb,
                            const float* __restrict__ w2, const float* __restrict__ b2,
                            short* __restrict__ Wfrag, float* __restrict__ Bset) {
    int L = blockIdx.x;        // 0..32
    int l = threadIdx.x;       // 0..63
    int op = l & 15;
    int q = l >> 4;
    int i0 = (q & 1) << 3;
    int tap = q >> 1;

    float gbuf[6][8];
#pragma unroll
    for (int j = 0; j < 8; ++j) {
        gbuf[0][j] = (L == 0) ? 0.f
                   : w1_post[((size_t)(L - 1) * 16 + op) * 16 + i0 + j];
        gbuf[1][j] = wf[(((size_t)L * 32 + op) * 16 + i0 + j) * 2 + tap];
        gbuf[2][j] = wf[(((size_t)L * 32 + 16 + op) * 16 + i0 + j) * 2 + tap];
        gbuf[3][j] = wg[(((size_t)L * 32 + op) * 16 + i0 + j) * 2 + tap];
        gbuf[4][j] = wg[(((size_t)L * 32 + 16 + op) * 16 + i0 + j) * 2 + tap];
        gbuf[5][j] = w2[((size_t)L * 16 + op) * 32 + (q << 3) + j];
    }

    constexpr int gsel[7] = {0, 0, 1, 2, 3, 4, 5};
    constexpr int hsel[7] = {1, 0, 1, 1, 1, 1, 1};
#pragma unroll
    for (int f = 0; f < 7; ++f) {
        size_t base = (((size_t)L * 7 + f) * 64 + l) * 8;
#pragma unroll
        for (int j = 0; j < 8; ++j) {
            float v = gbuf[gsel[f]][j];
            unsigned short h = bf16_rne(v);
            Wfrag[base + j] = hsel[f] ? (short)h
                                      : (short)bf16_rne(v - bf16_to_f(h));
        }
    }

#pragma unroll
    for (int r = 0; r < 4; ++r) {
        int c = (q << 2) + r;
        float bv[6];
        bv[0] = (L == 0) ? b1_first[c] : b1_post[(size_t)(L - 1) * 16 + c];
        bv[1] = bfb[(size_t)L * 32 + c];
        bv[2] = bfb[(size_t)L * 32 + 16 + c];
        bv[3] = bgb[(size_t)L * 32 + c];
        bv[4] = bgb[(size_t)L * 32 + 16 + c];
        bv[5] = b2[(size_t)L * 16 + c];
#pragma unroll
        for (int s = 0; s < 6; ++s)
            Bset[(((size_t)L * 6 + s) * 64 + l) * 4 + r] = bv[s];
    }
}

// ---------------------------------------------------------------------------
// conv1 at one position (column p of the segment). MODE 0/2: xin is the
// fragment-ready split-bf16 stream (64B/pos: hi 32B + lo 32B); B-frag is a
// single 16B load at offset q*16 (q<2: hi halves, q>=2: lo halves), matching
// A-frags f0 (W hi) and f1 (W lo): f0*b = Whi*x, f1*b = Wlo*x. OOB -> 0.
// ---------------------------------------------------------------------------
template <int MODE>
__device__ __forceinline__ f32x4 conv1_eval(const void* __restrict__ xin,
                                            const float* __restrict__ w1f,
                                            int b, int tp, int q,
                                            f32x4 b1v, bf16x8 A1, bf16x8 A2) {
    const f32x4 zero = {0.f, 0.f, 0.f, 0.f};
    bool valid = ((unsigned)tp) < (unsigned)TT;
    f32x4 acc = valid ? b1v : zero;
    if (MODE == 1) {
        const float* xf = (const float*)xin;
        float xv = valid ? xf[(size_t)b * TT + tp] : 0.f;
        const float4* w4 = (const float4*)w1f;
        float4 w = w4[q];
        acc[0] = fmaf(w.x, xv, acc[0]);
        acc[1] = fmaf(w.y, xv, acc[1]);
        acc[2] = fmaf(w.z, xv, acc[2]);
        acc[3] = fmaf(w.w, xv, acc[3]);
    } else {
        int tpc = valid ? tp : 0;
        const bf16x8 z8 = {0, 0, 0, 0, 0, 0, 0, 0};
        const bf16x8* xp = (const bf16x8*)((const char*)xin +
                            ((size_t)b * TT + tpc) * 64 + (q << 4));
        bf16x8 bb = valid ? *xp : z8;
        acc = MFMA(A1, bb, acc);
        acc = MFMA(A2, bb, acc);
    }
#pragma unroll
    for (int r = 0; r < 4; ++r) acc[r] = fmaxf(acc[r], 0.f);
    return acc;
}

// MODE: 0 = middle, 1 = first (raw (B,1,T) fp32 input), 2 = last
template <int MODE>
__global__ __launch_bounds__(256) void wn_layer(
    const void* __restrict__ xin, void* __restrict__ xout,
    float* __restrict__ skip, float* __restrict__ dout,
    const short* __restrict__ WfragL, const float* __restrict__ BsetL,
    const float* __restrict__ w1f, int d) {
    __shared__ char sm[8192];  // per wave: 1KB xr (2 segs x 512B) + 1KB z

    const int tid = threadIdx.x;
    const int wave = tid >> 6, lane = tid & 63;
    const int p = lane & 15, q = lane >> 4;

    // bijective XCD swizzle (8192 blocks % 8 == 0)
    const int blk = ((blockIdx.x & 7) << 10) + (blockIdx.x >> 3);
    const int b = blk >> 8;
    const int tbase = ((blk & 255) << 6) + (wave << 4);
    const int pl = d >> 1, pr = d - pl;

    char* xrb = sm + wave * 1024;
    char* zb = sm + 4096 + wave * 1024;
    const int xorb = (p & 8) << 2;  // bit-5 XOR: breaks p/p+8 bank aliasing

    const bf16x8* WF = (const bf16x8*)WfragL;
    const f32x4* BS = (const f32x4*)BsetL;

    const f32x4 b1v = BS[lane];
    bf16x8 A1 = {0, 0, 0, 0, 0, 0, 0, 0};
    bf16x8 A2 = {0, 0, 0, 0, 0, 0, 0, 0};
    if (MODE != 1) { A1 = WF[lane]; A2 = WF[64 + lane]; }

    // --- conv1 at the two tap segments -> xr (single bf16) in LDS
    // store: chunk c=q (4 ch) at seg*512 + (c>>1)*256 + p*16 + (c&1)*8, ^xorb
#pragma unroll
    for (int g = 0; g < 2; ++g) {
        int ts = tbase + (g ? pr : -pl);
        f32x4 xr = conv1_eval<MODE>(xin, w1f, b, ts + p, q, b1v, A1, A2);
        *(s16x4*)(xrb + (g << 9) +
                  ((((q >> 1) << 8) + (p << 4) + ((q & 1) << 3)) ^ xorb)) = pack4(xr);
    }

    f32x4 xrC = {0.f, 0.f, 0.f, 0.f};
    if (MODE != 2)
        xrC = conv1_eval<MODE>(xin, w1f, b, tbase + p, q, b1v, A1, A2);

    // --- gated dilated conv: B-frag lane(p,q) = xr[seg=q>>1][ch 8(q&1)..+7][p]
    bf16x8 bxr = *(const bf16x8*)(xrb + ((q >> 1) << 9) +
                                  ((((q & 1) << 8) + (p << 4)) ^ xorb));
    f32x4 f0 = BS[64 + lane], f1 = BS[128 + lane];
    f32x4 g0 = BS[192 + lane], g1 = BS[256 + lane];
    f0 = MFMA(WF[2 * 64 + lane], bxr, f0);
    f1 = MFMA(WF[3 * 64 + lane], bxr, f1);
    g0 = MFMA(WF[4 * 64 + lane], bxr, g0);
    g1 = MFMA(WF[5 * 64 + lane], bxr, g1);

    // --- z = tanh(f)*sigmoid(g) -> single bf16 in LDS
    f32x4 z0, z1;
#pragma unroll
    for (int r = 0; r < 4; ++r) {
        z0[r] = fast_tanh(f0[r]) * fast_sigmoid(g0[r]);
        z1[r] = fast_tanh(f1[r]) * fast_sigmoid(g1[r]);
    }
    {
        int base = (((q >> 1) << 8) + (p << 4) + ((q & 1) << 3)) ^ xorb;
        *(s16x4*)(zb + base) = pack4(z0);          // ch 4q..4q+3
        *(s16x4*)(zb + 512 + base) = pack4(z1);    // ch 16+4q..+3
    }

    // --- output 1x1 conv (32->16): B-frag = z[ch 8q..8q+7][p]
    bf16x8 bz = *(const bf16x8*)(zb + (((q << 8) + (p << 4)) ^ xorb));
    f32x4 z2 = MFMA(WF[6 * 64 + lane], bz, BS[320 + lane]);
#pragma unroll
    for (int r = 0; r < 4; ++r) z2[r] = fmaxf(z2[r], 0.f);

    // --- epilogue
    size_t pos = (size_t)b * TT + tbase + p;
    size_t xidx = (pos << 4) + (q << 2);  // fp32 skip layout (b,t,ch)
    if (MODE != 2) {
        f32x4 xo;
#pragma unroll
        for (int r = 0; r < 4; ++r) xo[r] = xrC[r] + z2[r];
        s16x4 xh, xl;
#pragma unroll
        for (int r = 0; r < 4; ++r) {
            unsigned short h = bf16_rne(xo[r]);
            xh[r] = (short)h;
            xl[r] = (short)bf16_rne(xo[r] - bf16_to_f(h));
        }
        char* xob = (char*)xout + pos * 64;
        *(s16x4*)(xob + (q << 3)) = xh;
        *(s16x4*)(xob + 32 + (q << 3)) = xl;
        if (MODE == 1) {
            *(f32x4*)(skip + xidx) = z2;
        } else {
            f32x4 s = *(const f32x4*)(skip + xidx);
#pragma unroll
            for (int r = 0; r < 4; ++r) s[r] += z2[r];
            *(f32x4*)(skip + xidx) = s;
        }
    } else {
        f32x4 s = *(const f32x4*)(skip + xidx);
        size_t ob = (size_t)b * (16 * (size_t)TT) + (size_t)(q << 2) * TT + (tbase + p);
#pragma unroll
        for (int r = 0; r < 4; ++r)
            dout[ob + (size_t)r * TT] = fmaxf(s[r] + z2[r], 0.f);
    }
}

extern "C" void kernel_launch(void* const* d_in, const int* in_sizes, int n_in,
                              void* d_out, int out_size, void* d_ws, size_t ws_size,
                              hipStream_t stream) {
    const float* x        = (const float*)d_in[0];
    const float* w1_first = (const float*)d_in[1];
    const float* b1_first = (const float*)d_in[2];
    const float* w1_post  = (const float*)d_in[3];
    const float* b1_post  = (const float*)d_in[4];
    const float* wf       = (const float*)d_in[5];
    const float* bf       = (const float*)d_in[6];
    const float* wg       = (const float*)d_in[7];
    const float* bg       = (const float*)d_in[8];
    const float* w2       = (const float*)d_in[9];
    const float* b2       = (const float*)d_in[10];

    void* X0 = d_ws;                                        // 33.55 MB (split-bf16 x)
    float* SK = (float*)((char*)d_ws + 33554432);           // 33.55 MB (fp32 skip)
    short* Wfrag = (short*)((char*)d_ws + 67108864);        // 236,544 B
    float* Bset = (float*)((char*)d_ws + 67345408);         // 202,752 B
    void* XD = d_out;  // ping-pong x buffer; overwritten by final layer

    prep_kernel<<<33, 64, 0, stream>>>(w1_first, b1_first, w1_post, b1_post,
                                       wf, bf, wg, bg, w2, b2, Wfrag, Bset);

    dim3 block(256);
    dim3 grid(BB * TT / 64);  // 8192

    for (int i = 0; i < 33; ++i) {
        int d = 1 << (i % 11);
        const void* xin = (i == 0) ? (const void*)x : ((i & 1) ? XD : X0);
        void* xout = (i & 1) ? X0 : XD;  // layer 0 writes XD
        const short* WfL = Wfrag + (size_t)i * 7 * 64 * 8;
        const float* BsL = Bset + (size_t)i * 6 * 64 * 4;

        if (i == 0) {
            wn_layer<1><<<grid, block, 0, stream>>>(xin, xout, SK, (float*)d_out,
                                                    WfL, BsL, w1_first, d);
        } else if (i == 32) {
            wn_layer<2><<<grid, block, 0, stream>>>(xin, nullptr, SK, (float*)d_out,
                                                    WfL, BsL, w1_first, d);
        } else {
            wn_layer<0><<<grid, block, 0, stream>>>(xin, xout, SK, (float*)d_out,
                                                    WfL, BsL, w1_first, d);
        }
    }
}

// Round 8
// 926.362 us; speedup vs baseline: 3.1724x; 1.0065x over previous
//
#include <hip/hip_runtime.h>
#include <hip/hip_cooperative_groups.h>

namespace cg = cooperative_groups;

#define BB 32
#define TT 16384

typedef __attribute__((ext_vector_type(8))) short bf16x8;
typedef __attribute__((ext_vector_type(4))) short s16x4;
typedef __attribute__((ext_vector_type(4))) float f32x4;

#define MFMA(A, B, C) __builtin_amdgcn_mfma_f32_16x16x32_bf16((A), (B), (C), 0, 0, 0)

__device__ __forceinline__ unsigned short bf16_rne(float f) {
    unsigned int u = __float_as_uint(f);
    return (unsigned short)((u + 0x7FFF + ((u >> 16) & 1)) >> 16);
}
__device__ __forceinline__ float bf16_to_f(unsigned short h) {
    return __uint_as_float(((unsigned int)h) << 16);
}
__device__ __forceinline__ s16x4 pack4(f32x4 v) {
    s16x4 r;
#pragma unroll
    for (int i = 0; i < 4; ++i) r[i] = (short)bf16_rne(v[i]);
    return r;
}

__device__ __forceinline__ float fast_sigmoid(float x) {
    float e = __expf(-x);
    return __builtin_amdgcn_rcpf(1.0f + e);
}
__device__ __forceinline__ float fast_tanh(float x) {
    float ax = fabsf(x);
    float e = __expf(2.0f * ax);
    float r = 1.0f - 2.0f * __builtin_amdgcn_rcpf(1.0f + e);
    return copysignf(r, x);
}

// ---------------------------------------------------------------------------
// Weight prep: 7 fragments + 6 bias sets per layer.
//   lane l: row = l&15 (out-ch), q = l>>4, elem j=0..7.
// f0/f1: conv1 W1 hi/lo:  src[j] = W1[row][8*(q&1)+j]
// f2..f5: gate Wf h0, Wf h1, Wg h0, Wg h1: src[j]=W[16h+row][8*(q&1)+j][q>>1]
// f6: out W2: src[j] = W2[row][8q+j]
// Bias sets: 0:b1  1:bf h0  2:bf h1  3:bg h0  4:bg h1  5:b2  (c = 4q+r)
// ---------------------------------------------------------------------------
__global__ void prep_kernel(const float* __restrict__ w1_first,
                            const float* __restrict__ b1_first,
                            const float* __restrict__ w1_post,
                            const float* __restrict__ b1_post,
                            const float* __restrict__ wf, const float* __restrict__ bfb,
                            const float* __restrict__ wg, const float* __restrict__ bgb,
                            const float* __restrict__ w2, const float* __restrict__ b2,
                            short* __restrict__ Wfrag, float* __restrict__ Bset) {
    int L = blockIdx.x;
    int l = threadIdx.x;
    int op = l & 15;
    int q = l >> 4;
    int i0 = (q & 1) << 3;
    int tap = q >> 1;

    float gbuf[6][8];
#pragma unroll
    for (int j = 0; j < 8; ++j) {
        gbuf[0][j] = (L == 0) ? 0.f
                   : w1_post[((size_t)(L - 1) * 16 + op) * 16 + i0 + j];
        gbuf[1][j] = wf[(((size_t)L * 32 + op) * 16 + i0 + j) * 2 + tap];
        gbuf[2][j] = wf[(((size_t)L * 32 + 16 + op) * 16 + i0 + j) * 2 + tap];
        gbuf[3][j] = wg[(((size_t)L * 32 + op) * 16 + i0 + j) * 2 + tap];
        gbuf[4][j] = wg[(((size_t)L * 32 + 16 + op) * 16 + i0 + j) * 2 + tap];
        gbuf[5][j] = w2[((size_t)L * 16 + op) * 32 + (q << 3) + j];
    }

    constexpr int gsel[7] = {0, 0, 1, 2, 3, 4, 5};
    constexpr int hsel[7] = {1, 0, 1, 1, 1, 1, 1};
#pragma unroll
    for (int f = 0; f < 7; ++f) {
        size_t base = (((size_t)L * 7 + f) * 64 + l) * 8;
#pragma unroll
        for (int j = 0; j < 8; ++j) {
            float v = gbuf[gsel[f]][j];
            unsigned short h = bf16_rne(v);
            Wfrag[base + j] = hsel[f] ? (short)h
                                      : (short)bf16_rne(v - bf16_to_f(h));
        }
    }

#pragma unroll
    for (int r = 0; r < 4; ++r) {
        int c = (q << 2) + r;
        float bv[6];
        bv[0] = (L == 0) ? b1_first[c] : b1_post[(size_t)(L - 1) * 16 + c];
        bv[1] = bfb[(size_t)L * 32 + c];
        bv[2] = bfb[(size_t)L * 32 + 16 + c];
        bv[3] = bgb[(size_t)L * 32 + c];
        bv[4] = bgb[(size_t)L * 32 + 16 + c];
        bv[5] = b2[(size_t)L * 16 + c];
#pragma unroll
        for (int s = 0; s < 6; ++s)
            Bset[(((size_t)L * 6 + s) * 64 + l) * 4 + r] = bv[s];
    }
}

// conv1 at one column. first==true: layer 0, fp32 (B,1,T) input via VALU.
// Otherwise split-bf16 fragment-ready stream (64B/pos), one 16B load.
__device__ __forceinline__ f32x4 conv1_eval(bool first, const void* __restrict__ xin,
                                            const float* __restrict__ w1f,
                                            int b, int tp, int q,
                                            f32x4 b1v, bf16x8 A1, bf16x8 A2) {
    const f32x4 zero = {0.f, 0.f, 0.f, 0.f};
    bool valid = ((unsigned)tp) < (unsigned)TT;
    f32x4 acc = valid ? b1v : zero;
    if (first) {
        const float* xf = (const float*)xin;
        float xv = valid ? xf[(size_t)b * TT + tp] : 0.f;
        const float4* w4 = (const float4*)w1f;
        float4 w = w4[q];
        acc[0] = fmaf(w.x, xv, acc[0]);
        acc[1] = fmaf(w.y, xv, acc[1]);
        acc[2] = fmaf(w.z, xv, acc[2]);
        acc[3] = fmaf(w.w, xv, acc[3]);
    } else {
        int tpc = valid ? tp : 0;
        const bf16x8 z8 = {0, 0, 0, 0, 0, 0, 0, 0};
        const bf16x8* xp = (const bf16x8*)((const char*)xin +
                            ((size_t)b * TT + tpc) * 64 + (q << 4));
        bf16x8 bb = valid ? *xp : z8;
        acc = MFMA(A1, bb, acc);
        acc = MFMA(A2, bb, acc);
    }
#pragma unroll
    for (int r = 0; r < 4; ++r) acc[r] = fmaxf(acc[r], 0.f);
    return acc;
}

// ===========================================================================
// FALLBACK PATH: one kernel per layer (verified at 932 us in round 6).
// MODE: 0 = middle, 1 = first (raw (B,1,T) fp32 input), 2 = last
// ===========================================================================
template <int MODE>
__global__ __launch_bounds__(256) void wn_layer(
    const void* __restrict__ xin, void* __restrict__ xout,
    float* __restrict__ skip, float* __restrict__ dout,
    const short* __restrict__ WfragL, const float* __restrict__ BsetL,
    const float* __restrict__ w1f, int d) {
    __shared__ char sm[8192];

    const int tid = threadIdx.x;
    const int wave = tid >> 6, lane = tid & 63;
    const int p = lane & 15, q = lane >> 4;

    const int blk = ((blockIdx.x & 7) << 10) + (blockIdx.x >> 3);
    const int b = blk >> 8;
    const int tbase = ((blk & 255) << 6) + (wave << 4);
    const int pl = d >> 1, pr = d - pl;

    char* xrb = sm + wave * 1024;
    char* zb = sm + 4096 + wave * 1024;
    const int xorb = (p & 8) << 2;

    const bf16x8* WF = (const bf16x8*)WfragL;
    const f32x4* BS = (const f32x4*)BsetL;

    const f32x4 b1v = BS[lane];
    bf16x8 A1 = {0, 0, 0, 0, 0, 0, 0, 0};
    bf16x8 A2 = {0, 0, 0, 0, 0, 0, 0, 0};
    if (MODE != 1) { A1 = WF[lane]; A2 = WF[64 + lane]; }

#pragma unroll
    for (int g = 0; g < 2; ++g) {
        int ts = tbase + (g ? pr : -pl);
        f32x4 xr = conv1_eval(MODE == 1, xin, w1f, b, ts + p, q, b1v, A1, A2);
        *(s16x4*)(xrb + (g << 9) +
                  ((((q >> 1) << 8) + (p << 4) + ((q & 1) << 3)) ^ xorb)) = pack4(xr);
    }

    f32x4 xrC = {0.f, 0.f, 0.f, 0.f};
    if (MODE != 2)
        xrC = conv1_eval(MODE == 1, xin, w1f, b, tbase + p, q, b1v, A1, A2);

    bf16x8 bxr = *(const bf16x8*)(xrb + ((q >> 1) << 9) +
                                  ((((q & 1) << 8) + (p << 4)) ^ xorb));
    f32x4 f0 = MFMA(WF[2 * 64 + lane], bxr, BS[64 + lane]);
    f32x4 f1 = MFMA(WF[3 * 64 + lane], bxr, BS[128 + lane]);
    f32x4 g0 = MFMA(WF[4 * 64 + lane], bxr, BS[192 + lane]);
    f32x4 g1 = MFMA(WF[5 * 64 + lane], bxr, BS[256 + lane]);

    f32x4 z0, z1;
#pragma unroll
    for (int r = 0; r < 4; ++r) {
        z0[r] = fast_tanh(f0[r]) * fast_sigmoid(g0[r]);
        z1[r] = fast_tanh(f1[r]) * fast_sigmoid(g1[r]);
    }
    {
        int base = (((q >> 1) << 8) + (p << 4) + ((q & 1) << 3)) ^ xorb;
        *(s16x4*)(zb + base) = pack4(z0);
        *(s16x4*)(zb + 512 + base) = pack4(z1);
    }

    bf16x8 bz = *(const bf16x8*)(zb + (((q << 8) + (p << 4)) ^ xorb));
    f32x4 z2 = MFMA(WF[6 * 64 + lane], bz, BS[320 + lane]);
#pragma unroll
    for (int r = 0; r < 4; ++r) z2[r] = fmaxf(z2[r], 0.f);

    size_t pos = (size_t)b * TT + tbase + p;
    size_t xidx = (pos << 4) + (q << 2);
    if (MODE != 2) {
        f32x4 xo;
#pragma unroll
        for (int r = 0; r < 4; ++r) xo[r] = xrC[r] + z2[r];
        s16x4 xh, xl;
#pragma unroll
        for (int r = 0; r < 4; ++r) {
            unsigned short h = bf16_rne(xo[r]);
            xh[r] = (short)h;
            xl[r] = (short)bf16_rne(xo[r] - bf16_to_f(h));
        }
        char* xob = (char*)xout + pos * 64;
        *(s16x4*)(xob + (q << 3)) = xh;
        *(s16x4*)(xob + 32 + (q << 3)) = xl;
        if (MODE == 1) {
            *(f32x4*)(skip + xidx) = z2;
        } else {
            f32x4 s = *(const f32x4*)(skip + xidx);
#pragma unroll
            for (int r = 0; r < 4; ++r) s[r] += z2[r];
            *(f32x4*)(skip + xidx) = s;
        }
    } else {
        f32x4 s = *(const f32x4*)(skip + xidx);
        size_t ob = (size_t)b * (16 * (size_t)TT) + (size_t)(q << 2) * TT + (tbase + p);
#pragma unroll
        for (int r = 0; r < 4; ++r)
            dout[ob + (size_t)r * TT] = fmaxf(s[r] + z2[r], 0.f);
    }
}

// ===========================================================================
// COOPERATIVE PATH: 512 blocks x 256 threads, 2 blocks/CU co-resident
// (launch_bounds(256,2) -> 256-VGPR budget, no occupancy cliff).
// Each wave owns 256 contiguous positions = 16 MFMA tiles; skip accumulator
// lives in VGPRs (sk[16], statically indexed via full unroll).
// ===========================================================================
__global__ __launch_bounds__(256, 2) void wn_all2(
    const float* __restrict__ x0, void* __restrict__ X0, void* __restrict__ XD,
    float* __restrict__ dout,
    const short* __restrict__ Wfrag, const float* __restrict__ Bset,
    const float* __restrict__ w1f) {
    cg::grid_group grid = cg::this_grid();

    __shared__ char sm[8192];

    const int tid = threadIdx.x;
    const int wave = tid >> 6, lane = tid & 63;
    const int p = lane & 15, q = lane >> 4;

    // bijective XCD swizzle over 512 blocks (8 chunks of 64)
    const int blk = ((blockIdx.x & 7) << 6) + (blockIdx.x >> 3);
    const int wbase = blk * 1024 + wave * 256;  // 256 contiguous positions/wave
    const int b = wbase >> 14;                  // constant per wave (256 | 16384)
    const int tb0 = wbase & (TT - 1);

    char* xrb = sm + wave * 1024;
    char* zb = sm + 4096 + wave * 1024;
    const int xorb = (p & 8) << 2;

    f32x4 sk[16];
#pragma unroll
    for (int k = 0; k < 16; ++k) sk[k] = f32x4{0.f, 0.f, 0.f, 0.f};

#pragma unroll 1
    for (int L = 0; L < 33; ++L) {
        const int d = 1 << (L % 11);
        const int pl = d >> 1, pr = d - pl;
        const bool first = (L == 0);
        const bool last = (L == 32);

        const bf16x8* WF = (const bf16x8*)(Wfrag + (size_t)L * 7 * 64 * 8);
        const f32x4* BS = (const f32x4*)(Bset + (size_t)L * 6 * 64 * 4);
        const void* xin = first ? (const void*)x0 : ((L & 1) ? XD : X0);
        void* xout = (L & 1) ? X0 : XD;  // layer 0 writes XD

        const f32x4 b1v = BS[lane];
        const f32x4 bf0 = BS[64 + lane], bf1 = BS[128 + lane];
        const f32x4 bg0 = BS[192 + lane], bg1 = BS[256 + lane];
        const f32x4 b2v = BS[320 + lane];
        bf16x8 A1 = {0, 0, 0, 0, 0, 0, 0, 0};
        bf16x8 A2 = {0, 0, 0, 0, 0, 0, 0, 0};
        if (!first) { A1 = WF[lane]; A2 = WF[64 + lane]; }
        const bf16x8 Wf0 = WF[2 * 64 + lane], Wf1 = WF[3 * 64 + lane];
        const bf16x8 Wg0 = WF[4 * 64 + lane], Wg1 = WF[5 * 64 + lane];
        const bf16x8 W2f = WF[6 * 64 + lane];

#pragma unroll
        for (int k = 0; k < 16; ++k) {
            const int tbase = tb0 + (k << 4);

            // conv1 at the two tap segments -> bf16 xr in LDS
#pragma unroll
            for (int g = 0; g < 2; ++g) {
                int ts = tbase + (g ? pr : -pl);
                f32x4 xr = conv1_eval(first, xin, w1f, b, ts + p, q, b1v, A1, A2);
                *(s16x4*)(xrb + (g << 9) +
                          ((((q >> 1) << 8) + (p << 4) + ((q & 1) << 3)) ^ xorb)) =
                    pack4(xr);
            }

            f32x4 xrC = {0.f, 0.f, 0.f, 0.f};
            if (!last)
                xrC = conv1_eval(first, xin, w1f, b, tbase + p, q, b1v, A1, A2);

            // gated dilated conv
            bf16x8 bxr = *(const bf16x8*)(xrb + ((q >> 1) << 9) +
                                          ((((q & 1) << 8) + (p << 4)) ^ xorb));
            f32x4 f0 = MFMA(Wf0, bxr, bf0);
            f32x4 f1 = MFMA(Wf1, bxr, bf1);
            f32x4 g0 = MFMA(Wg0, bxr, bg0);
            f32x4 g1 = MFMA(Wg1, bxr, bg1);

            f32x4 z0, z1;
#pragma unroll
            for (int r = 0; r < 4; ++r) {
                z0[r] = fast_tanh(f0[r]) * fast_sigmoid(g0[r]);
                z1[r] = fast_tanh(f1[r]) * fast_sigmoid(g1[r]);
            }
            {
                int base = (((q >> 1) << 8) + (p << 4) + ((q & 1) << 3)) ^ xorb;
                *(s16x4*)(zb + base) = pack4(z0);
                *(s16x4*)(zb + 512 + base) = pack4(z1);
            }

            // output 1x1 conv (32->16) + relu
            bf16x8 bz = *(const bf16x8*)(zb + (((q << 8) + (p << 4)) ^ xorb));
            f32x4 z2 = MFMA(W2f, bz, b2v);
#pragma unroll
            for (int r = 0; r < 4; ++r) z2[r] = fmaxf(z2[r], 0.f);

            // epilogue: residual write (split-bf16) + register skip accum
            if (!last) {
                size_t pos = (size_t)b * TT + tbase + p;
                f32x4 xo;
#pragma unroll
                for (int r = 0; r < 4; ++r) xo[r] = xrC[r] + z2[r];
                s16x4 xh, xl;
#pragma unroll
                for (int r = 0; r < 4; ++r) {
                    unsigned short h = bf16_rne(xo[r]);
                    xh[r] = (short)h;
                    xl[r] = (short)bf16_rne(xo[r] - bf16_to_f(h));
                }
                char* xob = (char*)xout + pos * 64;
                *(s16x4*)(xob + (q << 3)) = xh;
                *(s16x4*)(xob + 32 + (q << 3)) = xl;
            }
#pragma unroll
            for (int r = 0; r < 4; ++r) sk[k][r] += z2[r];
        }

        if (!last) grid.sync();
    }

    // final output: relu(skip_sum) in (B,16,T) layout
#pragma unroll
    for (int k = 0; k < 16; ++k) {
        size_t ob = (size_t)b * (16 * (size_t)TT) + (size_t)(q << 2) * TT +
                    (tb0 + (k << 4) + p);
#pragma unroll
        for (int r = 0; r < 4; ++r)
            dout[ob + (size_t)r * TT] = fmaxf(sk[k][r], 0.f);
    }
}

extern "C" void kernel_launch(void* const* d_in, const int* in_sizes, int n_in,
                              void* d_out, int out_size, void* d_ws, size_t ws_size,
                              hipStream_t stream) {
    const float* x        = (const float*)d_in[0];
    const float* w1_first = (const float*)d_in[1];
    const float* b1_first = (const float*)d_in[2];
    const float* w1_post  = (const float*)d_in[3];
    const float* b1_post  = (const float*)d_in[4];
    const float* wf       = (const float*)d_in[5];
    const float* bf       = (const float*)d_in[6];
    const float* wg       = (const float*)d_in[7];
    const float* bg       = (const float*)d_in[8];
    const float* w2       = (const float*)d_in[9];
    const float* b2       = (const float*)d_in[10];

    void* X0 = d_ws;                                    // 33.55 MB split-bf16 x
    float* SK = (float*)((char*)d_ws + 33554432);       // 33.55 MB fp32 skip (fallback)
    short* Wfrag = (short*)((char*)d_ws + 67108864);    // 236,544 B
    float* Bset = (float*)((char*)d_ws + 67345408);     // 202,752 B
    void* XD = d_out;
    float* dout = (float*)d_out;

    prep_kernel<<<33, 64, 0, stream>>>(w1_first, b1_first, w1_post, b1_post,
                                       wf, bf, wg, bg, w2, b2, Wfrag, Bset);

    // Decide coop vs fallback from pure host-side queries (capture-safe,
    // device-fixed -> deterministic).
    bool use_coop = false;
    {
        int dev = 0;
        hipGetDevice(&dev);
        int coop_attr = 0;
        hipDeviceGetAttribute(&coop_attr, hipDeviceAttributeCooperativeLaunch, dev);
        int blocks_per_cu = 0;
        hipOccupancyMaxActiveBlocksPerMultiprocessor(
            &blocks_per_cu, reinterpret_cast<const void*>(wn_all2), 256, 0);
        int num_cu = 0;
        hipDeviceGetAttribute(&num_cu, hipDeviceAttributeMultiprocessorCount, dev);
        use_coop = (coop_attr != 0) && ((long)blocks_per_cu * num_cu >= 512);
    }

    if (use_coop) {
        void* args[] = {(void*)&x, (void*)&X0, (void*)&XD, (void*)&dout,
                        (void*)&Wfrag, (void*)&Bset, (void*)&w1_first};
        hipError_t e = hipLaunchCooperativeKernel(
            reinterpret_cast<void*>(wn_all2), dim3(512), dim3(256), args, 0, stream);
        if (e == hipSuccess) return;
        // fall through to the multi-kernel path on failure
    }

    dim3 block(256);
    dim3 grid(BB * TT / 64);  // 8192
    for (int i = 0; i < 33; ++i) {
        int d = 1 << (i % 11);
        const void* xin = (i == 0) ? (const void*)x : ((i & 1) ? XD : X0);
        void* xout = (i & 1) ? X0 : XD;
        const short* WfL = Wfrag + (size_t)i * 7 * 64 * 8;
        const float* BsL = Bset + (size_t)i * 6 * 64 * 4;
        if (i == 0) {
            wn_layer<1><<<grid, block, 0, stream>>>(xin, xout, SK, dout,
                                                    WfL, BsL, w1_first, d);
        } else if (i == 32) {
            wn_layer<2><<<grid, block, 0, stream>>>(xin, nullptr, SK, dout,
                                                    WfL, BsL, w1_first, d);
        } else {
            wn_layer<0><<<grid, block, 0, stream>>>(xin, xout, SK, dout,
                                                    WfL, BsL, w1_first, d);
        }
    }
}

// Round 9
// 803.569 us; speedup vs baseline: 3.6572x; 1.1528x over previous
//
#include <hip/hip_runtime.h>

#define BB 32
#define TT 16384

typedef __attribute__((ext_vector_type(8))) short bf16x8;
typedef __attribute__((ext_vector_type(4))) short s16x4;
typedef __attribute__((ext_vector_type(4))) float f32x4;
typedef __attribute__((ext_vector_type(4))) int i32x4;

#define MFMA(A, B, C) __builtin_amdgcn_mfma_f32_16x16x32_bf16((A), (B), (C), 0, 0, 0)

__device__ __forceinline__ unsigned short bf16_rne(float f) {
    unsigned int u = __float_as_uint(f);
    return (unsigned short)((u + 0x7FFF + ((u >> 16) & 1)) >> 16);
}
__device__ __forceinline__ float bf16_to_f(unsigned short h) {
    return __uint_as_float(((unsigned int)h) << 16);
}
__device__ __forceinline__ s16x4 pack4(f32x4 v) {
    s16x4 r;
#pragma unroll
    for (int i = 0; i < 4; ++i) r[i] = (short)bf16_rne(v[i]);
    return r;
}

__device__ __forceinline__ float fast_sigmoid(float x) {
    float e = __expf(-x);
    return __builtin_amdgcn_rcpf(1.0f + e);
}
__device__ __forceinline__ float fast_tanh(float x) {
    float ax = fabsf(x);
    float e = __expf(2.0f * ax);
    float r = 1.0f - 2.0f * __builtin_amdgcn_rcpf(1.0f + e);
    return copysignf(r, x);
}

// ---------------------------------------------------------------------------
// Weight prep (verified round 6): 7 fragments + 6 bias sets per layer.
//   lane l: row = l&15 (out-ch), q = l>>4, elem j=0..7.
// f0/f1: conv1 W1 hi/lo:  src[j] = W1[row][8*(q&1)+j]
// f2..f5: gate Wf h0, Wf h1, Wg h0, Wg h1: src[j]=W[16h+row][8*(q&1)+j][q>>1]
// f6: out W2: src[j] = W2[row][8q+j]
// Bias sets: 0:b1  1:bf h0  2:bf h1  3:bg h0  4:bg h1  5:b2  (c = 4q+r)
// ---------------------------------------------------------------------------
__global__ void prep_kernel(const float* __restrict__ w1_first,
                            const float* __restrict__ b1_first,
                            const float* __restrict__ w1_post,
                            const float* __restrict__ b1_post,
                            const float* __restrict__ wf, const float* __restrict__ bfb,
                            const float* __restrict__ wg, const float* __restrict__ bgb,
                            const float* __restrict__ w2, const float* __restrict__ b2,
                            short* __restrict__ Wfrag, float* __restrict__ Bset) {
    int L = blockIdx.x;
    int l = threadIdx.x;
    int op = l & 15;
    int q = l >> 4;
    int i0 = (q & 1) << 3;
    int tap = q >> 1;

    float gbuf[6][8];
#pragma unroll
    for (int j = 0; j < 8; ++j) {
        gbuf[0][j] = (L == 0) ? 0.f
                   : w1_post[((size_t)(L - 1) * 16 + op) * 16 + i0 + j];
        gbuf[1][j] = wf[(((size_t)L * 32 + op) * 16 + i0 + j) * 2 + tap];
        gbuf[2][j] = wf[(((size_t)L * 32 + 16 + op) * 16 + i0 + j) * 2 + tap];
        gbuf[3][j] = wg[(((size_t)L * 32 + op) * 16 + i0 + j) * 2 + tap];
        gbuf[4][j] = wg[(((size_t)L * 32 + 16 + op) * 16 + i0 + j) * 2 + tap];
        gbuf[5][j] = w2[((size_t)L * 16 + op) * 32 + (q << 3) + j];
    }

    constexpr int gsel[7] = {0, 0, 1, 2, 3, 4, 5};
    constexpr int hsel[7] = {1, 0, 1, 1, 1, 1, 1};
#pragma unroll
    for (int f = 0; f < 7; ++f) {
        size_t base = (((size_t)L * 7 + f) * 64 + l) * 8;
#pragma unroll
        for (int j = 0; j < 8; ++j) {
            float v = gbuf[gsel[f]][j];
            unsigned short h = bf16_rne(v);
            Wfrag[base + j] = hsel[f] ? (short)h
                                      : (short)bf16_rne(v - bf16_to_f(h));
        }
    }

#pragma unroll
    for (int r = 0; r < 4; ++r) {
        int c = (q << 2) + r;
        float bv[6];
        bv[0] = (L == 0) ? b1_first[c] : b1_post[(size_t)(L - 1) * 16 + c];
        bv[1] = bfb[(size_t)L * 32 + c];
        bv[2] = bfb[(size_t)L * 32 + 16 + c];
        bv[3] = bgb[(size_t)L * 32 + c];
        bv[4] = bgb[(size_t)L * 32 + 16 + c];
        bv[5] = b2[(size_t)L * 16 + c];
#pragma unroll
        for (int s = 0; s < 6; ++s)
            Bset[(((size_t)L * 6 + s) * 64 + l) * 4 + r] = bv[s];
    }
}

// conv1 at one column (verified round 6). first: layer 0, fp32 (B,1,T) input.
__device__ __forceinline__ f32x4 conv1_eval(bool first, const void* __restrict__ xin,
                                            const float* __restrict__ w1f,
                                            int b, int tp, int q,
                                            f32x4 b1v, bf16x8 A1, bf16x8 A2) {
    const f32x4 zero = {0.f, 0.f, 0.f, 0.f};
    bool valid = ((unsigned)tp) < (unsigned)TT;
    f32x4 acc = valid ? b1v : zero;
    if (first) {
        const float* xf = (const float*)xin;
        float xv = valid ? xf[(size_t)b * TT + tp] : 0.f;
        const float4* w4 = (const float4*)w1f;
        float4 w = w4[q];
        acc[0] = fmaf(w.x, xv, acc[0]);
        acc[1] = fmaf(w.y, xv, acc[1]);
        acc[2] = fmaf(w.z, xv, acc[2]);
        acc[3] = fmaf(w.w, xv, acc[3]);
    } else {
        int tpc = valid ? tp : 0;
        const bf16x8 z8 = {0, 0, 0, 0, 0, 0, 0, 0};
        const bf16x8* xp = (const bf16x8*)((const char*)xin +
                            ((size_t)b * TT + tpc) * 64 + (q << 4));
        bf16x8 bb = valid ? *xp : z8;
        acc = MFMA(A1, bb, acc);
        acc = MFMA(A2, bb, acc);
    }
#pragma unroll
    for (int r = 0; r < 4; ++r) acc[r] = fmaxf(acc[r], 0.f);
    return acc;
}

// ===========================================================================
// SINGLE-LAYER kernel (verified round 6, 8192 blocks).
// MODE: 0 = middle, 1 = first (raw fp32 input), 2 = last
// ===========================================================================
template <int MODE>
__global__ __launch_bounds__(256) void wn_layer(
    const void* __restrict__ xin, void* __restrict__ xout,
    float* __restrict__ skip, float* __restrict__ dout,
    const short* __restrict__ WfragL, const float* __restrict__ BsetL,
    const float* __restrict__ w1f, int d) {
    __shared__ char sm[8192];

    const int tid = threadIdx.x;
    const int wave = tid >> 6, lane = tid & 63;
    const int p = lane & 15, q = lane >> 4;

    const int blk = ((blockIdx.x & 7) << 10) + (blockIdx.x >> 3);
    const int b = blk >> 8;
    const int tbase = ((blk & 255) << 6) + (wave << 4);
    const int pl = d >> 1, pr = d - pl;

    char* xrb = sm + wave * 1024;
    char* zb = sm + 4096 + wave * 1024;
    const int xorb = (p & 8) << 2;

    const bf16x8* WF = (const bf16x8*)WfragL;
    const f32x4* BS = (const f32x4*)BsetL;

    const f32x4 b1v = BS[lane];
    bf16x8 A1 = {0, 0, 0, 0, 0, 0, 0, 0};
    bf16x8 A2 = {0, 0, 0, 0, 0, 0, 0, 0};
    if (MODE != 1) { A1 = WF[lane]; A2 = WF[64 + lane]; }

#pragma unroll
    for (int g = 0; g < 2; ++g) {
        int ts = tbase + (g ? pr : -pl);
        f32x4 xr = conv1_eval(MODE == 1, xin, w1f, b, ts + p, q, b1v, A1, A2);
        *(s16x4*)(xrb + (g << 9) +
                  ((((q >> 1) << 8) + (p << 4) + ((q & 1) << 3)) ^ xorb)) = pack4(xr);
    }

    f32x4 xrC = {0.f, 0.f, 0.f, 0.f};
    if (MODE != 2)
        xrC = conv1_eval(MODE == 1, xin, w1f, b, tbase + p, q, b1v, A1, A2);

    bf16x8 bxr = *(const bf16x8*)(xrb + ((q >> 1) << 9) +
                                  ((((q & 1) << 8) + (p << 4)) ^ xorb));
    f32x4 f0 = MFMA(WF[2 * 64 + lane], bxr, BS[64 + lane]);
    f32x4 f1 = MFMA(WF[3 * 64 + lane], bxr, BS[128 + lane]);
    f32x4 g0 = MFMA(WF[4 * 64 + lane], bxr, BS[192 + lane]);
    f32x4 g1 = MFMA(WF[5 * 64 + lane], bxr, BS[256 + lane]);

    f32x4 z0, z1;
#pragma unroll
    for (int r = 0; r < 4; ++r) {
        z0[r] = fast_tanh(f0[r]) * fast_sigmoid(g0[r]);
        z1[r] = fast_tanh(f1[r]) * fast_sigmoid(g1[r]);
    }
    {
        int base = (((q >> 1) << 8) + (p << 4) + ((q & 1) << 3)) ^ xorb;
        *(s16x4*)(zb + base) = pack4(z0);
        *(s16x4*)(zb + 512 + base) = pack4(z1);
    }

    bf16x8 bz = *(const bf16x8*)(zb + (((q << 8) + (p << 4)) ^ xorb));
    f32x4 z2 = MFMA(WF[6 * 64 + lane], bz, BS[320 + lane]);
#pragma unroll
    for (int r = 0; r < 4; ++r) z2[r] = fmaxf(z2[r], 0.f);

    size_t pos = (size_t)b * TT + tbase + p;
    size_t xidx = (pos << 4) + (q << 2);
    if (MODE != 2) {
        f32x4 xo;
#pragma unroll
        for (int r = 0; r < 4; ++r) xo[r] = xrC[r] + z2[r];
        s16x4 xh, xl;
#pragma unroll
        for (int r = 0; r < 4; ++r) {
            unsigned short h = bf16_rne(xo[r]);
            xh[r] = (short)h;
            xl[r] = (short)bf16_rne(xo[r] - bf16_to_f(h));
        }
        char* xob = (char*)xout + pos * 64;
        *(s16x4*)(xob + (q << 3)) = xh;
        *(s16x4*)(xob + 32 + (q << 3)) = xl;
        if (MODE == 1) {
            *(f32x4*)(skip + xidx) = z2;
        } else {
            f32x4 s = *(const f32x4*)(skip + xidx);
#pragma unroll
            for (int r = 0; r < 4; ++r) s[r] += z2[r];
            *(f32x4*)(skip + xidx) = s;
        }
    } else {
        f32x4 s = *(const f32x4*)(skip + xidx);
        size_t ob = (size_t)b * (16 * (size_t)TT) + (size_t)(q << 2) * TT + (tbase + p);
#pragma unroll
        for (int r = 0; r < 4; ++r)
            dout[ob + (size_t)r * TT] = fmaxf(s[r] + z2[r], 0.f);
    }
}

// ===========================================================================
// FUSED kernel: NL consecutive layers (dilations 1<<(d0p+k)), trapezoid halo.
// Region = 768 positions (48 tiles of 16); final output = tiles [8,40).
// LDS (dynamic 77824B):
//   A: x split-bf16, 4 planes [hi ch0-7][hi ch8-15][lo ch0-7][lo ch8-15],
//      each 768*16B = 12288.  (in-place x update; same-wave access only)
//   U: u single-bf16, 2 planes [ch0-7][ch8-15], each 12288. (cross-wave taps)
//   z: per-wave 1KB staging (as singles).
// Wave w owns tiles T = 4m+w (m=0..11); skip accumulates in sk[8] (m=2..9).
// ===========================================================================
__global__ __launch_bounds__(256, 2) void wn_fused(
    const char* __restrict__ Xin, char* __restrict__ Xout,
    float* __restrict__ skip,
    const short* __restrict__ Wfrag, const float* __restrict__ Bset,
    int Lbase, int d0p, int NL) {
    extern __shared__ char sm[];
    char* Abuf = sm;            // 49152
    char* Ubuf = sm + 49152;    // 24576

    const int tid = threadIdx.x;
    const int wave = tid >> 6, lane = tid & 63;
    const int p = lane & 15, q = lane >> 4;
    char* zb = sm + 73728 + wave * 1024;
    const int xorb = (p & 8) << 2;

    // bijective XCD swizzle over 1024 blocks
    const int gblk = ((blockIdx.x & 7) << 7) | (blockIdx.x >> 3);
    const int b = gblk >> 5;
    const int gt0 = ((gblk & 31) << 9) - 128;  // global t of local pos 0

    // phase 0: cooperative load of x region into A (zero outside sequence)
#pragma unroll
    for (int jj = 0; jj < 3; ++jj) {
        int pos = jj * 256 + tid;
        int g = gt0 + pos;
        bool valid = ((unsigned)g) < (unsigned)TT;
        const char* src = Xin + ((size_t)b * TT + (valid ? g : 0)) * 64;
#pragma unroll
        for (int sub = 0; sub < 4; ++sub) {
            i32x4 v = {0, 0, 0, 0};
            if (valid) v = *(const i32x4*)(src + sub * 16);
            *(i32x4*)(Abuf + sub * 12288 + pos * 16) = v;
        }
    }
    __syncthreads();

    int uLo = 0, uHi = 48;
    f32x4 sk[8];
#pragma unroll
    for (int m = 0; m < 8; ++m) sk[m] = f32x4{0.f, 0.f, 0.f, 0.f};

#pragma unroll 1
    for (int k = 0; k < NL; ++k) {
        const int L = Lbase + k;
        const int d = 1 << (d0p + k);
        const int pl = d >> 1, pr = d - pl;
        const int tl = (pl + 15) >> 4, tr = (pr + 15) >> 4;
        const bool lastk = (k == NL - 1);
        const int nLo = uLo + tl, nHi = uHi - tr;

        const bf16x8* WF = (const bf16x8*)(Wfrag + (size_t)L * 7 * 64 * 8);
        const f32x4* BS = (const f32x4*)(Bset + (size_t)L * 6 * 64 * 4);
        const bf16x8 A1 = WF[lane], A2 = WF[64 + lane];
        const bf16x8 Wf0 = WF[128 + lane], Wf1 = WF[192 + lane];
        const bf16x8 Wg0 = WF[256 + lane], Wg1 = WF[320 + lane];
        const bf16x8 W2f = WF[384 + lane];
        const f32x4 b1v = BS[lane];
        const f32x4 bf0 = BS[64 + lane], bf1 = BS[128 + lane];
        const f32x4 bg0 = BS[192 + lane], bg1 = BS[256 + lane];
        const f32x4 b2v = BS[320 + lane];

        // --- phase a: u = relu(conv1(x)) over [uLo,uHi) -> U (bf16)
#pragma unroll
        for (int m = 0; m < 12; ++m) {
            int T = 4 * m + wave;
            if (T >= uLo && T < uHi) {
                int pos = T * 16 + p;
                bf16x8 bb = *(const bf16x8*)(Abuf + q * 12288 + pos * 16);
                f32x4 acc = b1v;
                acc = MFMA(A1, bb, acc);
                acc = MFMA(A2, bb, acc);
                bool val = ((unsigned)(gt0 + pos)) < (unsigned)TT;
                s16x4 uu;
#pragma unroll
                for (int r = 0; r < 4; ++r) {
                    float u = val ? fmaxf(acc[r], 0.f) : 0.f;
                    uu[r] = (short)bf16_rne(u);
                }
                *(s16x4*)(Ubuf + (q >> 1) * 12288 + pos * 16 + ((q & 1) << 3)) = uu;
            }
        }
        __syncthreads();

        // --- phase b: gate + out conv + residual (in-place A) + skip regs
#pragma unroll
        for (int m = 0; m < 12; ++m) {
            int T = 4 * m + wave;
            bool doit = lastk ? (m >= 2 && m <= 9) : (T >= nLo && T < nHi);
            if (doit) {
                int pos = T * 16 + p;
                int tap = (q >> 1) ? pr : -pl;
                bf16x8 bxr = *(const bf16x8*)(Ubuf + (q & 1) * 12288 + (pos + tap) * 16);
                f32x4 f0 = MFMA(Wf0, bxr, bf0);
                f32x4 f1 = MFMA(Wf1, bxr, bf1);
                f32x4 g0 = MFMA(Wg0, bxr, bg0);
                f32x4 g1 = MFMA(Wg1, bxr, bg1);

                f32x4 z0, z1;
#pragma unroll
                for (int r = 0; r < 4; ++r) {
                    z0[r] = fast_tanh(f0[r]) * fast_sigmoid(g0[r]);
                    z1[r] = fast_tanh(f1[r]) * fast_sigmoid(g1[r]);
                }
                int zbase = (((q >> 1) << 8) + (p << 4) + ((q & 1) << 3)) ^ xorb;
                *(s16x4*)(zb + zbase) = pack4(z0);
                *(s16x4*)(zb + 512 + zbase) = pack4(z1);
                bf16x8 bz = *(const bf16x8*)(zb + (((q << 8) + (p << 4)) ^ xorb));
                f32x4 z2 = MFMA(W2f, bz, b2v);
#pragma unroll
                for (int r = 0; r < 4; ++r) z2[r] = fmaxf(z2[r], 0.f);

                // recompute uC (fp32) for the residual
                bf16x8 bc = *(const bf16x8*)(Abuf + q * 12288 + pos * 16);
                f32x4 uc = b1v;
                uc = MFMA(A1, bc, uc);
                uc = MFMA(A2, bc, uc);
                int g = gt0 + pos;
                bool val = ((unsigned)g) < (unsigned)TT;
                f32x4 xo;
#pragma unroll
                for (int r = 0; r < 4; ++r)
                    xo[r] = (val ? fmaxf(uc[r], 0.f) : 0.f) + z2[r];

                s16x4 xh, xl;
#pragma unroll
                for (int r = 0; r < 4; ++r) {
                    unsigned short h = bf16_rne(xo[r]);
                    xh[r] = (short)h;
                    xl[r] = (short)bf16_rne(xo[r] - bf16_to_f(h));
                }
                if (!lastk) {
                    *(s16x4*)(Abuf + (q >> 1) * 12288 + pos * 16 + ((q & 1) << 3)) = xh;
                    *(s16x4*)(Abuf + (2 + (q >> 1)) * 12288 + pos * 16 + ((q & 1) << 3)) = xl;
                } else {
                    char* gx = Xout + ((size_t)b * TT + g) * 64;
                    *(s16x4*)(gx + (q >> 1) * 16 + ((q & 1) << 3)) = xh;
                    *(s16x4*)(gx + 32 + (q >> 1) * 16 + ((q & 1) << 3)) = xl;
                }
                if (m >= 2 && m <= 9) sk[m - 2] += z2;
            }
        }
        __syncthreads();
        uLo = nLo;
        uHi = nHi;
    }

    // skip RMW: one fp32 read+write per position for all NL layers
#pragma unroll
    for (int m = 2; m <= 9; ++m) {
        int T = 4 * m + wave;
        int g = gt0 + T * 16 + p;
        float* sp = skip + (((size_t)b * TT + g) << 4) + (q << 2);
        f32x4 s = *(const f32x4*)sp;
#pragma unroll
        for (int r = 0; r < 4; ++r) s[r] += sk[m - 2][r];
        *(f32x4*)sp = s;
    }
}

extern "C" void kernel_launch(void* const* d_in, const int* in_sizes, int n_in,
                              void* d_out, int out_size, void* d_ws, size_t ws_size,
                              hipStream_t stream) {
    const float* x        = (const float*)d_in[0];
    const float* w1_first = (const float*)d_in[1];
    const float* b1_first = (const float*)d_in[2];
    const float* w1_post  = (const float*)d_in[3];
    const float* b1_post  = (const float*)d_in[4];
    const float* wf       = (const float*)d_in[5];
    const float* bf       = (const float*)d_in[6];
    const float* wg       = (const float*)d_in[7];
    const float* bg       = (const float*)d_in[8];
    const float* w2       = (const float*)d_in[9];
    const float* b2       = (const float*)d_in[10];

    void* X0 = d_ws;                                    // 33.55 MB split-bf16 x
    float* SK = (float*)((char*)d_ws + 33554432);       // 33.55 MB fp32 skip
    short* Wfrag = (short*)((char*)d_ws + 67108864);    // 236,544 B
    float* Bset = (float*)((char*)d_ws + 67345408);     // 202,752 B
    void* XD = d_out;                                   // x ping-pong partner
    float* dout = (float*)d_out;

    // allow 76KB dynamic LDS for the fused kernel (no-op if already set)
    static bool attr_done = false;
    if (!attr_done) {
        hipFuncSetAttribute(reinterpret_cast<const void*>(wn_fused),
                            hipFuncAttributeMaxDynamicSharedMemorySize, 77824);
        attr_done = true;
    }

    prep_kernel<<<33, 64, 0, stream>>>(w1_first, b1_first, w1_post, b1_post,
                                       wf, bf, wg, bg, w2, b2, Wfrag, Bset);

    dim3 sblock(256), sgrid(BB * TT / 64);   // singles: 8192 blocks
    dim3 fblock(256), fgrid(BB * TT / 512);  // fused: 1024 blocks

    // launch plan: out buffer = X0 at even n, XD at odd n (n = launch index)
    // n: 0=L0(M1) 1=fused(1-6) 2..5=L7-10 6=fused(11-17) 7..10=L18-21
    //    11=fused(22-28) 12..14=L29-31 15=L32(M2)
    int n = 0;
    const void* cur_in = (const void*)x;
    auto nxt = [&](int parity) -> void* { return (parity & 1) ? XD : X0; };

    // L0 single, MODE 1
    {
        void* out = nxt(n);
        wn_layer<1><<<sgrid, sblock, 0, stream>>>(cur_in, out, SK, dout,
                                                  Wfrag, Bset, w1_first, 1);
        cur_in = out; n ^= 1;
    }
    for (int cyc = 0; cyc < 3; ++cyc) {
        int Lb = (cyc == 0) ? 1 : 11 * cyc;
        int d0p = (cyc == 0) ? 1 : 0;
        int NL = (cyc == 0) ? 6 : 7;
        // fused small-d run
        {
            void* out = nxt(n);
            wn_fused<<<fgrid, fblock, 77824, stream>>>(
                (const char*)cur_in, (char*)out, SK, Wfrag, Bset, Lb, d0p, NL);
            cur_in = out; n ^= 1;
        }
        // large-d singles: layers Lb+NL .. cycle end
        int Ls = Lb + NL;           // 7, 18, 29
        for (int L = Ls; L <= Ls + 3; ++L) {
            int d = 1 << (L % 11);
            const short* WfL = Wfrag + (size_t)L * 7 * 64 * 8;
            const float* BsL = Bset + (size_t)L * 6 * 64 * 4;
            if (L == 32) {
                wn_layer<2><<<sgrid, sblock, 0, stream>>>(cur_in, nullptr, SK, dout,
                                                          WfL, BsL, w1_first, d);
            } else {
                void* out = nxt(n);
                wn_layer<0><<<sgrid, sblock, 0, stream>>>(cur_in, out, SK, dout,
                                                          WfL, BsL, w1_first, d);
                cur_in = out; n ^= 1;
            }
        }
    }
}